// Round 8
// baseline (94.939 us; speedup 1.0000x reference)
//
#include <hip/hip_runtime.h>

typedef float f32x4 __attribute__((ext_vector_type(4)));
typedef __bf16 bf16x8 __attribute__((ext_vector_type(8)));
typedef unsigned short u16x4 __attribute__((ext_vector_type(4)));
typedef unsigned int u32x4 __attribute__((ext_vector_type(4)));

constexpr int V  = 4096;
constexpr int KS = 5;               // K-split (slabs 832,832,832,832,768)
constexpr int NSLAB = 3 * KS;       // 15 partial slabs

__device__ __forceinline__ unsigned short f2bf(float f) {
    unsigned int u = __float_as_uint(f);
    u += 0x7FFFu + ((u >> 16) & 1u);           // round-to-nearest-even
    return (unsigned short)(u >> 16);
}
__device__ __forceinline__ float bf2f(unsigned short h) {
    return __uint_as_float(((unsigned int)h) << 16);
}

// ---- kernel 1: z = W @ xv + b  -> bf16 (384 x 4096) --------------------
__global__ __launch_bounds__(256) void k_z(const float* __restrict__ x,
                                           const float* __restrict__ W,
                                           const float* __restrict__ b,
                                           unsigned short* __restrict__ zb) {
    __shared__ float Ws[8 * 128];
    __shared__ float bs[8];
    const int rg = blockIdx.x;
    const int vb = blockIdx.y;
    const int t  = threadIdx.x;
    reinterpret_cast<f32x4*>(Ws)[t] = reinterpret_cast<const f32x4*>(W + rg * 1024)[t];
    if (t < 8) bs[t] = b[rg * 8 + t];
    __syncthreads();
    const int v = vb * 1024 + t * 4;
    f32x4 acc[8] = {};
    #pragma unroll 8
    for (int j = 0; j < 128; ++j) {
        f32x4 xv = *reinterpret_cast<const f32x4*>(x + (size_t)j * V + v);
        #pragma unroll
        for (int q = 0; q < 8; ++q) acc[q] += Ws[q * 128 + j] * xv;
    }
    #pragma unroll
    for (int q = 0; q < 8; ++q) {
        u16x4 u;
        #pragma unroll
        for (int j = 0; j < 4; ++j) u[j] = f2bf(acc[q][j] + bs[q]);
        *reinterpret_cast<u16x4*>(zb + (size_t)(rg * 8 + q) * V + v) = u;
    }
}

// ---- kernel 2: partial[p,kh] = bf16( z[p] @ A[p][k-slab] ) -------------
// grid (16 nt, 3 p, 5 kh) = 240 blocks, 256 thr = 4 waves (2M x 2N).
// Tile 128M x 256N, BK=32. Every A-load instruction = 1 KB contiguous burst
// (r7 finding: burst size is the BW lever), and every phase issues the NEXT
// A-tile BEFORE the vmcnt wait on the current one (r6 schedule: next tile is
// always a full phase deep when we stall). FIFO-traced: no wait drains a
// live prefetch.
__global__ __launch_bounds__(256, 1) void k_gemm(const unsigned short* __restrict__ zb,
                                                 const float* __restrict__ A,
                                                 unsigned short* __restrict__ partial) {
    // [buf][n(256)][kpair(16) @ pitch 20 u32]  = 40 KB total
    // kp-quad swizzle: stored kp = logical kp XOR (((n>>2)&3)<<2)
    __shared__ unsigned int Bt[2][256][20];

    const int nt = blockIdx.x;     // 0..15
    const int p  = blockIdx.y;     // 0..2
    const int kh = blockIdx.z;     // 0..4
    const int n0    = nt * 256;
    const int kbase = kh * 832;
    const int kend  = (kh == 4) ? 4096 : kbase + 832;

    const int t  = threadIdx.x;
    const int w  = t >> 6;
    const int l  = t & 63;
    const int wm = w >> 1, wn = w & 1;
    const int lrow = l & 15, g = l >> 4;

    // staging read base: rows k + w*8 + j, cols n0 + 4l (1 KB/wave-instr)
    const float* Ab = A + (size_t)p * V * V + (size_t)(w * 8) * V + n0 + l * 4;
    // staging write: n = 4l+q, kp-quad = 4*(w ^ (l&3)); one b128 per q
    const int wswz = (w ^ (l & 3)) << 2;
    // fragment read: n = wn*128 + nn*16 + lrow; swizzled kp-quad:
    const int gp = (g ^ ((lrow >> 2) & 3)) << 2;
    // z fragments: rows m = wm*64 + mt*16 + lrow, k-offset g*8
    const unsigned short* Zb = zb + ((size_t)p * 128 + wm * 64 + lrow) * V + g * 8;

    f32x4 acc[4][8] = {};
    f32x4 arA[8], arB[8];
    bf16x8 zrA[4], zrB[4];

#define LOADA(AR, K) { _Pragma("unroll") for (int j = 0; j < 8; ++j) \
        AR[j] = *reinterpret_cast<const f32x4*>(Ab + (size_t)((K) + j) * V); }

#define LOADZ(ZR, K) { _Pragma("unroll") for (int mt = 0; mt < 4; ++mt) \
        ZR[mt] = *reinterpret_cast<const bf16x8*>(Zb + (size_t)mt * 16 * V + (K)); }

#define WRITEB(B, AR) { _Pragma("unroll") for (int q = 0; q < 4; ++q) { \
        u32x4 pk; \
        asm("v_cvt_pk_bf16_f32 %0, %1, %2" : "=v"(pk[0]) : "v"(AR[0][q]), "v"(AR[1][q])); \
        asm("v_cvt_pk_bf16_f32 %0, %1, %2" : "=v"(pk[1]) : "v"(AR[2][q]), "v"(AR[3][q])); \
        asm("v_cvt_pk_bf16_f32 %0, %1, %2" : "=v"(pk[2]) : "v"(AR[4][q]), "v"(AR[5][q])); \
        asm("v_cvt_pk_bf16_f32 %0, %1, %2" : "=v"(pk[3]) : "v"(AR[6][q]), "v"(AR[7][q])); \
        *reinterpret_cast<u32x4*>(&Bt[B][l * 4 + q][wswz]) = pk; } }

#define BAR asm volatile("s_waitcnt lgkmcnt(0)\n\ts_barrier" ::: "memory")

#define MFMAP(B, ZR) { _Pragma("unroll") for (int nn = 0; nn < 8; ++nn) { \
        bf16x8 bf = *reinterpret_cast<const bf16x8*>(&Bt[B][wn * 128 + nn * 16 + lrow][gp]); \
        _Pragma("unroll") for (int mt = 0; mt < 4; ++mt) \
            acc[mt][nn] = __builtin_amdgcn_mfma_f32_16x16x32_bf16(ZR[mt], bf, acc[mt][nn], 0, 0, 0); } }

    // prologue (issue order = FIFO order): zrA(k0), arA(k0), zrB(k0+32)
    LOADZ(zrA, kbase);
    LOADA(arA, kbase);
    LOADZ(zrB, kbase + 32);

    for (int k0 = kbase; k0 < kend; k0 += 64) {
        const int k2 = (k0 + 64 < kend) ? k0 + 64 : kbase;   // dead-load clamp
        const int k3 = (k0 + 96 < kend) ? k0 + 96 : kbase;
        // ---- phase 0: consume arA(k0), zrA(k0) ----
        LOADA(arB, k0 + 32);       // issue next tile FIRST — overlaps arA's wait
        WRITEB(0, arA);            // waits arA (drains zrA too — needed now anyway)
        BAR;
        MFMAP(0, zrA);
        LOADZ(zrA, k2);            // z for next iter phase 0
        // ---- phase 1: consume arB(k0+32), zrB(k0+32) ----
        LOADA(arA, k2);            // issue next-next tile before arB's wait
        WRITEB(1, arB);            // waits arB (drains zrB — needed now anyway)
        BAR;
        MFMAP(1, zrB);
        LOADZ(zrB, k3);
    }

    // C/D layout: col = lane&15 (n), row = g*4 + reg (m)  [verified r1..r7]
    unsigned short* Pp = partial + (size_t)(p * KS + kh) * 128 * V;
    #pragma unroll
    for (int mt = 0; mt < 4; ++mt)
        #pragma unroll
        for (int nn = 0; nn < 8; ++nn) {
            const size_t base = (size_t)(wm * 64 + mt * 16 + g * 4) * V
                              + n0 + wn * 128 + nn * 16 + lrow;
            #pragma unroll
            for (int r = 0; r < 4; ++r)
                Pp[base + (size_t)r * V] = f2bf(acc[mt][nn][r]);
        }
#undef LOADA
#undef LOADZ
#undef WRITEB
#undef BAR
#undef MFMAP
}

// ---- kernel 3: out = relu(x + sum(fifo[:48 slabs]) + sum(15 bf16 partials))
__global__ __launch_bounds__(256) void k_epi(const float* __restrict__ x,
                                             const float* __restrict__ fifo,
                                             const unsigned short* __restrict__ partial,
                                             float* __restrict__ out) {
    const size_t off  = ((size_t)blockIdx.x * 256 + threadIdx.x) * 4;
    const size_t slab = (size_t)128 * V;
    f32x4 s0 = *reinterpret_cast<const f32x4*>(x + off);
    f32x4 s1 = {}, s2 = {}, s3 = {};
    #pragma unroll
    for (int s = 0; s < 48; ++s) {   // fifo[:16] x 3p = first 48 slabs
        f32x4 fv = *reinterpret_cast<const f32x4*>(fifo + (size_t)s * slab + off);
        switch (s & 3) {
            case 0: s0 += fv; break;
            case 1: s1 += fv; break;
            case 2: s2 += fv; break;
            default: s3 += fv; break;
        }
    }
    #pragma unroll
    for (int q = 0; q < NSLAB; ++q) {
        u16x4 pv = *reinterpret_cast<const u16x4*>(partial + (size_t)q * slab + off);
        f32x4 d;
        #pragma unroll
        for (int j = 0; j < 4; ++j) d[j] = bf2f(pv[j]);
        if (q & 1) s1 += d; else s2 += d;
    }
    f32x4 sum = (s0 + s1) + (s2 + s3);
    f32x4 o;
    #pragma unroll
    for (int j = 0; j < 4; ++j) o[j] = fmaxf(sum[j], 0.0f);
    *reinterpret_cast<f32x4*>(out + off) = o;
}

extern "C" void kernel_launch(void* const* d_in, const int* in_sizes, int n_in,
                              void* d_out, int out_size, void* d_ws, size_t ws_size,
                              hipStream_t stream) {
    const float* x    = (const float*)d_in[0];   // (1,128,4096,1)
    const float* A    = (const float*)d_in[1];   // (3,4096,4096)
    const float* fifo = (const float*)d_in[2];   // (17,3,128,4096)
    const float* W    = (const float*)d_in[3];   // (384,128)
    const float* b    = (const float*)d_in[4];   // (384,)
    float* out = (float*)d_out;                  // (1,128,4096) f32

    unsigned short* zb      = (unsigned short*)d_ws;                                    // 3 MB bf16
    unsigned short* partial = (unsigned short*)((char*)d_ws + (size_t)3 * 1024 * 1024); // 15 MB bf16

    k_z   <<<dim3(48, 4),     256, 0, stream>>>(x, W, b, zb);
    k_gemm<<<dim3(16, 3, KS), 256, 0, stream>>>(zb, A, partial);
    k_epi <<<dim3(512),       256, 0, stream>>>(x, fifo, partial, out);
}